// Round 8
// baseline (241.663 us; speedup 1.0000x reference)
//
#include <hip/hip_runtime.h>
#include <hip/hip_bf16.h>

#define BB 64
#define TT 512
#define EE 768
#define CC 20
#define MID 256

typedef __attribute__((ext_vector_type(8))) short bf16x8;
typedef __attribute__((ext_vector_type(4))) float f32x4;

__device__ __forceinline__ float rlane(float x, int l) {
  return __int_as_float(__builtin_amdgcn_readlane(__float_as_int(x), l));
}
__device__ __forceinline__ float bcast(float x, int a4) {
  return __int_as_float(__builtin_amdgcn_ds_bpermute(a4, __float_as_int(x)));
}
__device__ __forceinline__ short f2bf(float x) {
  union { __hip_bfloat16 h; short s; } u;
  u.h = __float2bfloat16(x);
  return u.s;
}
__device__ __forceinline__ bf16x8 pack8(float4 a, float4 b) {
  bf16x8 r;
  r[0] = f2bf(a.x); r[1] = f2bf(a.y); r[2] = f2bf(a.z); r[3] = f2bf(a.w);
  r[4] = f2bf(b.x); r[5] = f2bf(b.y); r[6] = f2bf(b.z); r[7] = f2bf(b.w);
  return r;
}

// ---------------- pre-pack fc_w into B-fragment layout (bf16); zero loss slot
__global__ __launch_bounds__(256) void packw_kernel(const float* __restrict__ fc_w,
                                                    short* __restrict__ wfrag,
                                                    float* __restrict__ outp) {
  if (blockIdx.x == 0 && threadIdx.x == 0) outp[0] = 0.f;  // finish accumulates here
  int t = blockIdx.x * 256 + threadIdx.x;  // 0 .. 2*24*64-1
  int lane = t & 63;
  int kc = (t >> 6) % 24;
  int tile = t / (24 * 64);
  int n = tile * 16 + (lane & 15);
  if (n >= CC) n = CC - 1;
  int k0 = kc * 32 + (lane >> 4) * 8;
  const float* src = fc_w + (size_t)n * EE + k0;
  float4 x = *(const float4*)src;
  float4 y = *(const float4*)(src + 4);
  ((bf16x8*)wfrag)[t] = pack8(x, y);
}

// ---------------- emissions: 4 waves/block, 64 tokens/block, W direct from L2.
__global__ __launch_bounds__(256) void emissions_kernel(
    const float* __restrict__ hidden, const short* __restrict__ wfrag,
    const float* __restrict__ fc_b, float* __restrict__ em) {
  const int wave = threadIdx.x >> 6;
  const int lane = threadIdx.x & 63;
  const int token0 = blockIdx.x * 64 + wave * 16;
  const int m = lane & 15, q = lane >> 4;
  const float* hrow = hidden + (size_t)(token0 + m) * EE + q * 8;
  const bf16x8* wp = (const bf16x8*)wfrag;  // 48 KiB, L2-resident broadcast
  f32x4 acc0 = {0.f, 0.f, 0.f, 0.f}, acc1 = {0.f, 0.f, 0.f, 0.f};
#pragma unroll 4
  for (int kb = 0; kb < 24; ++kb) {
    float4 a0 = *(const float4*)(hrow + kb * 32);
    float4 a1 = *(const float4*)(hrow + kb * 32 + 4);
    bf16x8 Ab = pack8(a0, a1);
    bf16x8 w0 = wp[kb * 64 + lane];
    bf16x8 w1 = wp[(24 + kb) * 64 + lane];
    acc0 = __builtin_amdgcn_mfma_f32_16x16x32_bf16(Ab, w0, acc0, 0, 0, 0);
    acc1 = __builtin_amdgcn_mfma_f32_16x16x32_bf16(Ab, w1, acc1, 0, 0, 0);
  }
  const int col = lane & 15;
  const float b0v = fc_b[col];
  const bool has1 = (16 + col < CC);
  const float b1v = has1 ? fc_b[16 + col] : 0.f;
#pragma unroll
  for (int r = 0; r < 4; ++r) {
    int tok = token0 + q * 4 + r;
    em[(size_t)tok * CC + col] = acc0[r] + b0v;
    if (has1) em[(size_t)tok * CC + 16 + col] = acc1[r] + b1v;
  }
}

// ---- bpermute broadcast: r0..r19 = state of lanes 0..19, in every lane.
// Pull-only (no ds_write on the chain); addresses are loop-invariant VGPRs.
#define GATHER20(x)                                                              \
  float r0 = bcast(x, 0), r1 = bcast(x, 4), r2 = bcast(x, 8), r3 = bcast(x, 12), \
        r4 = bcast(x, 16), r5 = bcast(x, 20), r6 = bcast(x, 24),                 \
        r7 = bcast(x, 28), r8 = bcast(x, 32), r9 = bcast(x, 36),                 \
        r10 = bcast(x, 40), r11 = bcast(x, 44), r12 = bcast(x, 48),              \
        r13 = bcast(x, 52), r14 = bcast(x, 56), r15 = bcast(x, 60),              \
        r16 = bcast(x, 64), r17 = bcast(x, 68), r18 = bcast(x, 72),              \
        r19 = bcast(x, 76);

// dot(r, ET): same accumulator grouping/order as before -> bitwise identical.
#define FDOT20(ET, out)                                                          \
  {                                                                              \
    float s0 = r0 * ET[0], s1 = r1 * ET[1], s2 = r2 * ET[2], s3 = r3 * ET[3];    \
    s0 = fmaf(r4, ET[4], s0); s1 = fmaf(r5, ET[5], s1);                          \
    s2 = fmaf(r6, ET[6], s2); s3 = fmaf(r7, ET[7], s3);                          \
    s0 = fmaf(r8, ET[8], s0); s1 = fmaf(r9, ET[9], s1);                          \
    s2 = fmaf(r10, ET[10], s2); s3 = fmaf(r11, ET[11], s3);                      \
    s0 = fmaf(r12, ET[12], s0); s1 = fmaf(r13, ET[13], s1);                      \
    s2 = fmaf(r14, ET[14], s2); s3 = fmaf(r15, ET[15], s3);                      \
    s0 = fmaf(r16, ET[16], s0); s1 = fmaf(r17, ET[17], s1);                      \
    s2 = fmaf(r18, ET[18], s2); s3 = fmaf(r19, ET[19], s3);                      \
    out = (s0 + s1) + (s2 + s3);                                                 \
  }

__device__ __forceinline__ unsigned umax_(unsigned a, unsigned b) { return a > b ? a : b; }
__device__ __forceinline__ unsigned umax3_(unsigned a, unsigned b, unsigned c) {
  return umax_(umax_(a, b), c);
}
// packed-u32 argmax over r0..r19 + tv (VCC-free); positive-biased inputs.
#define VSTEP20(tv, vmo, jmo)                                                    \
  {                                                                              \
    float v0 = r0 + tv[0], v1 = r1 + tv[1], v2 = r2 + tv[2], v3 = r3 + tv[3];    \
    float v4 = r4 + tv[4], v5 = r5 + tv[5], v6 = r6 + tv[6], v7 = r7 + tv[7];    \
    float v8 = r8 + tv[8], v9 = r9 + tv[9], v10 = r10 + tv[10];                  \
    float v11 = r11 + tv[11], v12 = r12 + tv[12], v13 = r13 + tv[13];            \
    float v14 = r14 + tv[14], v15 = r15 + tv[15], v16 = r16 + tv[16];            \
    float v17 = r17 + tv[17], v18 = r18 + tv[18], v19 = r19 + tv[19];            \
    unsigned p0 = (__float_as_uint(v0) & 0xFFFFFFE0u) | 0u;                      \
    unsigned p1 = (__float_as_uint(v1) & 0xFFFFFFE0u) | 1u;                      \
    unsigned p2 = (__float_as_uint(v2) & 0xFFFFFFE0u) | 2u;                      \
    unsigned p3 = (__float_as_uint(v3) & 0xFFFFFFE0u) | 3u;                      \
    unsigned p4 = (__float_as_uint(v4) & 0xFFFFFFE0u) | 4u;                      \
    unsigned p5 = (__float_as_uint(v5) & 0xFFFFFFE0u) | 5u;                      \
    unsigned p6 = (__float_as_uint(v6) & 0xFFFFFFE0u) | 6u;                      \
    unsigned p7 = (__float_as_uint(v7) & 0xFFFFFFE0u) | 7u;                      \
    unsigned p8 = (__float_as_uint(v8) & 0xFFFFFFE0u) | 8u;                      \
    unsigned p9 = (__float_as_uint(v9) & 0xFFFFFFE0u) | 9u;                      \
    unsigned p10 = (__float_as_uint(v10) & 0xFFFFFFE0u) | 10u;                   \
    unsigned p11 = (__float_as_uint(v11) & 0xFFFFFFE0u) | 11u;                   \
    unsigned p12 = (__float_as_uint(v12) & 0xFFFFFFE0u) | 12u;                   \
    unsigned p13 = (__float_as_uint(v13) & 0xFFFFFFE0u) | 13u;                   \
    unsigned p14 = (__float_as_uint(v14) & 0xFFFFFFE0u) | 14u;                   \
    unsigned p15 = (__float_as_uint(v15) & 0xFFFFFFE0u) | 15u;                   \
    unsigned p16 = (__float_as_uint(v16) & 0xFFFFFFE0u) | 16u;                   \
    unsigned p17 = (__float_as_uint(v17) & 0xFFFFFFE0u) | 17u;                   \
    unsigned p18 = (__float_as_uint(v18) & 0xFFFFFFE0u) | 18u;                   \
    unsigned p19 = (__float_as_uint(v19) & 0xFFFFFFE0u) | 19u;                   \
    unsigned m0 = umax3_(p0, p1, p2);                                            \
    unsigned m1 = umax3_(p3, p4, p5);                                            \
    unsigned m2 = umax3_(p6, p7, p8);                                            \
    unsigned m3 = umax3_(p9, p10, p11);                                          \
    unsigned m4 = umax3_(p12, p13, p14);                                         \
    unsigned m5 = umax3_(p15, p16, p17);                                         \
    unsigned n0 = umax3_(m0, m1, m2);                                            \
    unsigned n1 = umax3_(m3, m4, m5);                                            \
    unsigned n2 = umax_(p18, p19);                                               \
    unsigned rr = umax3_(n0, n1, n2);                                            \
    vmo = __uint_as_float(rr & 0xFFFFFFE0u);                                     \
    jmo = (int)(rr & 31u);                                                       \
  }

#define XDECL(Q) float x##Q = rlane(x, Q); int y##Q = Q;
#define MRX(A_, B_) { bool k_ = (x##A_ >= x##B_); x##A_ = k_ ? x##A_ : x##B_; y##A_ = k_ ? y##A_ : y##B_; }
__device__ __forceinline__ int lane_argmax(float x) {
  XDECL(0) XDECL(1) XDECL(2) XDECL(3) XDECL(4) XDECL(5) XDECL(6) XDECL(7)
  XDECL(8) XDECL(9) XDECL(10) XDECL(11) XDECL(12) XDECL(13) XDECL(14)
  XDECL(15) XDECL(16) XDECL(17) XDECL(18) XDECL(19)
  MRX(0, 10) MRX(1, 11) MRX(2, 12) MRX(3, 13) MRX(4, 14)
  MRX(5, 15) MRX(6, 16) MRX(7, 17) MRX(8, 18) MRX(9, 19)
  MRX(0, 5) MRX(1, 6) MRX(2, 7) MRX(3, 8) MRX(4, 9)
  MRX(0, 1) MRX(2, 3)
  MRX(0, 2) MRX(0, 4)
  return y0;
}

// ---------------- CRF halves. quad: 0=fwd-fore 1=fwd-back 2=vit-fore 3=vit-back
// State broadcast via ds_bpermute pull (no ds_write on the recurrence chain).
// Branch-free renorm from r0 (broadcast state[0]); unconditional clamped stores.
__global__ __launch_bounds__(64) void crf_half_kernel(
    const float* __restrict__ em, const int* __restrict__ mask,
    const float* __restrict__ st, const float* __restrict__ en,
    const float* __restrict__ tr,
    float* __restrict__ amw, float* __restrict__ bmw,
    float* __restrict__ avw, float* __restrict__ bvw,
    unsigned char* __restrict__ bpws, unsigned char* __restrict__ fpws) {
  __shared__ __align__(16) float emsh[(MID + 1) * CC];  // fore rows 0..256 / back rows 256..511
  __shared__ int msh[TT];
  const int tid = threadIdx.x;
  const int quad = blockIdx.x >> 6;
  const int b = blockIdx.x & (BB - 1);
  const int back = quad & 1;
  const int cc = tid < CC ? tid : CC - 1;
  const float K = 1.44269504088896340736f;
  const float BIAS = 64.0f;

  {
    const float* base = em + (size_t)b * TT * CC + (back ? MID * CC : 0);
    int nf4 = back ? (MID * CC / 4) : ((MID + 1) * CC / 4);  // 1280 or 1285
    const float4* src = (const float4*)base;
    float4* dst = (float4*)emsh;
    for (int i = tid; i < nf4; i += 64) dst[i] = src[i];
    for (int i = tid; i < TT; i += 64) msh[i] = mask[b * TT + i];
  }
  __syncthreads();

  if (quad == 0) {
    // ===== forward alpha, t=1..MID, linear domain, per-step pow2 renorm =====
    float ET[CC];
#pragma unroll
    for (int q = 0; q < CC; ++q) ET[q] = __builtin_amdgcn_exp2f(tr[q * CC + cc] * K);
    float r = st[cc] + emsh[cc];
    float base0 = rlane(r, 0);
    float Es = __builtin_amdgcn_exp2f((r - base0) * K);
    float off = base0 * K;
    int ie = 0;
    float eec = __builtin_amdgcn_exp2f(emsh[CC + cc] * K);
    int mcur = msh[1];
    for (int t = 1; t <= MID; ++t) {
      GATHER20(Es)
      int xb = __float_as_int(r0);  // broadcast state[0]: exact pow2 renorm
      int e = ((xb >> 23) & 255) - 127;
      float scale = __int_as_float((127 - e) << 23);
      int tn = (t < MID) ? t + 1 : t;
      float emn = emsh[tn * CC + cc];
      int mn = msh[tn];
      float s;
      FDOT20(ET, s)
      s *= eec;
      float sn = s * scale;
      float Eold = Es * scale;
      Es = mcur ? sn : Eold;
      ie += e;
      eec = __builtin_amdgcn_exp2f(emn * K);
      mcur = mn;
    }
    if (tid < CC) amw[b * CC + tid] = off + (float)ie + __builtin_amdgcn_logf(Es);
  } else if (quad == 1) {
    // ===== backward beta, t=T-2..MID, linear, mask-reset to en, pow2 renorm =====
    float ETr[CC];
#pragma unroll
    for (int q = 0; q < CC; ++q) ETr[q] = __builtin_amdgcn_exp2f(tr[cc * CC + q] * K);
    const float ENc = __builtin_amdgcn_exp2f(en[cc] * K);
    float Bs = ENc;
    int ie = 0;
    float ee1 = __builtin_amdgcn_exp2f(emsh[(TT - 1 - MID) * CC + cc] * K);  // exp(em_511)
    int m1 = msh[TT - 1];
    for (int t = TT - 2; t >= MID; --t) {
      float G = Bs * ee1;
      GATHER20(G)
      int xb = __float_as_int(r0);  // broadcast G[0]
      int e = ((xb >> 23) & 255) - 127;
      float scale = __int_as_float((127 - e) << 23);
      float emn = emsh[(t - MID) * CC + cc];  // em_t
      int mn = msh[t];
      float s;
      FDOT20(ETr, s)
      float bsn = s * scale;
      Bs = m1 ? bsn : ENc;
      ie = m1 ? (ie + e) : 0;
      ee1 = __builtin_amdgcn_exp2f(emn * K);
      m1 = mn;
    }
    if (tid < CC) bmw[b * CC + tid] = (float)ie + __builtin_amdgcn_logf(Bs);
  } else if (quad == 2) {
    // ===== viterbi fore, t=1..MID, per-step uniform re-centering =====
    float tv[CC];
#pragma unroll
    for (int q = 0; q < CC; ++q) tv[q] = tr[q * CC + cc];
    float a = st[cc] + emsh[cc] + BIAS;
    float emc = emsh[CC + cc];
    int mcur = msh[1];
    unsigned char* bp = bpws + (size_t)b * MID * CC;
    for (int t = 1; t <= MID; ++t) {
      GATHER20(a)
      float shift = BIAS - r0;  // uniform: argmax/backpointer-invariant
      int tn = (t < MID) ? t + 1 : t;
      float emn = emsh[tn * CC + cc];
      int mn = msh[tn];
      float vm;
      int jm;
      VSTEP20(tv, vm, jm)
      float adc = emc + shift;   // off critical path
      float aold = a + shift;
      float au = vm + adc;
      a = mcur ? au : aold;
      bp[(t - 1) * CC + cc] = (unsigned char)jm;  // clamped col: lanes>=20 dup lane19
      emc = emn;
      mcur = mn;
    }
    if (tid < CC) avw[b * CC + tid] = a;
  } else {
    // ===== viterbi back, t=T-2..MID, per-step uniform re-centering =====
    float tv[CC];
#pragma unroll
    for (int q = 0; q < CC; ++q) tv[q] = tr[cc * CC + q];  // row of tr
    const float ENv = en[cc] + BIAS;
    float Vb = ENv;
    float em1 = emsh[(TT - 1 - MID) * CC + cc];
    int m1 = msh[TT - 1];
    unsigned char* fp = fpws + (size_t)b * MID * CC;
    for (int t = TT - 2; t >= MID; --t) {
      float av = Vb + em1;
      GATHER20(av)
      float shift = BIAS - r0;
      float emn = emsh[(t - MID) * CC + cc];
      int mn = msh[t];
      float vm;
      int jm;
      VSTEP20(tv, vm, jm)
      float vs = vm + shift;
      Vb = m1 ? vs : ENv;        // masked: exact reset to ENv
      fp[(t - MID) * CC + cc] = (unsigned char)jm;
      em1 = emn;
      m1 = mn;
    }
    if (tid < CC) bvw[b * CC + tid] = Vb;
  }
}

// ---------------- finish: join halves, backtrace both ways, numerator, llh, loss
__global__ __launch_bounds__(64) void finish_kernel(
    const float* __restrict__ em, const int* __restrict__ mask,
    const int* __restrict__ labels, const float* __restrict__ st,
    const float* __restrict__ en, const float* __restrict__ tr,
    const float* __restrict__ amw, const float* __restrict__ bmw,
    const float* __restrict__ avw, const float* __restrict__ bvw,
    const unsigned char* __restrict__ bpws, const unsigned char* __restrict__ fpws,
    float* __restrict__ out) {
  __shared__ unsigned char hl[2 * MID * CC];  // 10240
  const int b = blockIdx.x;
  const int tid = threadIdx.x;
  const int cc = tid < CC ? tid : CC - 1;
  const float LN2 = 0.69314718055994530942f;
  {
    const int4* bsrc = (const int4*)(bpws + (size_t)b * MID * CC);
    const int4* fsrc = (const int4*)(fpws + (size_t)b * MID * CC);
    int4* dst = (int4*)hl;
    for (int i = tid; i < 320; i += 64) {
      dst[i] = bsrc[i];
      dst[320 + i] = fsrc[i];
    }
  }
  __syncthreads();

  // --- viterbi join + dual backtrace ---
  int cstar = lane_argmax(avw[b * CC + cc] + bvw[b * CC + cc]);
  float* ob = out + 1 + (size_t)b * TT;
  if (tid == 0) ob[MID] = (float)(cstar + 1);
  // backward: s = 255..0, tag_s = bp[s][tag_{s+1}] ; 256 = 32*8 exact
  {
    int tag = cstar;
    int s = MID - 1;
    while (s >= 7) {
      int g0 = hl[(s - 0) * CC + cc];
      int g1 = hl[(s - 1) * CC + cc];
      int g2 = hl[(s - 2) * CC + cc];
      int g3 = hl[(s - 3) * CC + cc];
      int g4 = hl[(s - 4) * CC + cc];
      int g5 = hl[(s - 5) * CC + cc];
      int g6 = hl[(s - 6) * CC + cc];
      int g7 = hl[(s - 7) * CC + cc];
      tag = __builtin_amdgcn_readlane(g0, tag); float f0 = (float)(tag + 1);
      tag = __builtin_amdgcn_readlane(g1, tag); float f1 = (float)(tag + 1);
      tag = __builtin_amdgcn_readlane(g2, tag); float f2 = (float)(tag + 1);
      tag = __builtin_amdgcn_readlane(g3, tag); float f3 = (float)(tag + 1);
      tag = __builtin_amdgcn_readlane(g4, tag); float f4 = (float)(tag + 1);
      tag = __builtin_amdgcn_readlane(g5, tag); float f5 = (float)(tag + 1);
      tag = __builtin_amdgcn_readlane(g6, tag); float f6 = (float)(tag + 1);
      tag = __builtin_amdgcn_readlane(g7, tag); float f7 = (float)(tag + 1);
      if (tid == 0) {
        ob[s - 0] = f0; ob[s - 1] = f1; ob[s - 2] = f2; ob[s - 3] = f3;
        ob[s - 4] = f4; ob[s - 5] = f5; ob[s - 6] = f6; ob[s - 7] = f7;
      }
      s -= 8;
    }
  }
  // forward: u = 0..254, tag_{t+1} = fp[u][tag_t], t = MID+u
  {
    int tag = cstar;
    int u = 0;
    while (u + 7 <= MID - 2) {
      int g0 = hl[MID * CC + (u + 0) * CC + cc];
      int g1 = hl[MID * CC + (u + 1) * CC + cc];
      int g2 = hl[MID * CC + (u + 2) * CC + cc];
      int g3 = hl[MID * CC + (u + 3) * CC + cc];
      int g4 = hl[MID * CC + (u + 4) * CC + cc];
      int g5 = hl[MID * CC + (u + 5) * CC + cc];
      int g6 = hl[MID * CC + (u + 6) * CC + cc];
      int g7 = hl[MID * CC + (u + 7) * CC + cc];
      tag = __builtin_amdgcn_readlane(g0, tag); float f0 = (float)(tag + 1);
      tag = __builtin_amdgcn_readlane(g1, tag); float f1 = (float)(tag + 1);
      tag = __builtin_amdgcn_readlane(g2, tag); float f2 = (float)(tag + 1);
      tag = __builtin_amdgcn_readlane(g3, tag); float f3 = (float)(tag + 1);
      tag = __builtin_amdgcn_readlane(g4, tag); float f4 = (float)(tag + 1);
      tag = __builtin_amdgcn_readlane(g5, tag); float f5 = (float)(tag + 1);
      tag = __builtin_amdgcn_readlane(g6, tag); float f6 = (float)(tag + 1);
      tag = __builtin_amdgcn_readlane(g7, tag); float f7 = (float)(tag + 1);
      if (tid == 0) {
        ob[MID + 1 + u + 0] = f0; ob[MID + 1 + u + 1] = f1;
        ob[MID + 1 + u + 2] = f2; ob[MID + 1 + u + 3] = f3;
        ob[MID + 1 + u + 4] = f4; ob[MID + 1 + u + 5] = f5;
        ob[MID + 1 + u + 6] = f6; ob[MID + 1 + u + 7] = f7;
      }
      u += 8;
    }
    while (u <= MID - 2) {
      int g = hl[MID * CC + u * CC + cc];
      tag = __builtin_amdgcn_readlane(g, tag);
      if (tid == 0) ob[MID + 1 + u] = (float)(tag + 1);
      ++u;
    }
  }

  // --- norm = LN2 * lse2(am + bm) ---
  float zn = amw[b * CC + cc] + bmw[b * CC + cc];
  float M = zn;
#pragma unroll
  for (int o = 32; o >= 1; o >>= 1) M = fmaxf(M, __shfl_xor(M, o));
  float sE = (tid < CC) ? __builtin_amdgcn_exp2f(zn - M) : 0.f;
#pragma unroll
  for (int o = 32; o >= 1; o >>= 1) sE += __shfl_xor(sE, o);
  float norm = LN2 * (M + __builtin_amdgcn_logf(sE));

  // --- numerator ---
  const int* lab = labels + b * TT;
  const float* emg = em + (size_t)b * TT * CC;
  float sc = 0.f;
  int msum = 0;
  for (int k = tid; k < TT; k += 64) {
    int mk = mask[b * TT + k];
    msum += mk;
    if (k >= 1) {
      int tg = lab[k], tp = lab[k - 1];
      sc += (tr[tp * CC + tg] + emg[k * CC + tg]) * (float)mk;
    }
  }
#pragma unroll
  for (int o = 32; o >= 1; o >>= 1) {
    sc += __shfl_xor(sc, o);
    msum += __shfl_xor(msum, o);
  }
  int seq_end = msum - 1;
  int t0 = lab[0], tl = lab[seq_end];
  float score = sc + st[t0] + emg[t0] + en[tl];
  // loss = mean(norm - score); out[0] pre-zeroed by packw_kernel
  if (tid == 0) atomicAdd(out, (norm - score) * (1.0f / 64.0f));
}

extern "C" void kernel_launch(void* const* d_in, const int* in_sizes, int n_in,
                              void* d_out, int out_size, void* d_ws, size_t ws_size,
                              hipStream_t stream) {
  const float* hidden = (const float*)d_in[0];
  const int* amask = (const int*)d_in[1];
  const int* labels = (const int*)d_in[2];
  const float* fc_w = (const float*)d_in[3];
  const float* fc_b = (const float*)d_in[4];
  const float* st = (const float*)d_in[5];
  const float* en = (const float*)d_in[6];
  const float* tr = (const float*)d_in[7];

  float* emws = (float*)d_ws;                          // 655360 floats
  float* llh = emws + (size_t)BB * TT * CC;            // 64 (unused, keeps layout)
  short* wfrag = (short*)(llh + 64);                   // 24576 shorts
  float* amw = (float*)(wfrag + 24576);                // 1280
  float* bmw = amw + BB * CC;
  float* avw = bmw + BB * CC;
  float* bvw = avw + BB * CC;
  unsigned char* bpws = (unsigned char*)(bvw + BB * CC);  // 327680 B (16B aligned)
  unsigned char* fpws = bpws + (size_t)BB * MID * CC;     // 327680 B
  float* out = (float*)d_out;

  packw_kernel<<<(2 * 24 * 64) / 256, 256, 0, stream>>>(fc_w, wfrag, out);
  emissions_kernel<<<(BB * TT) / 64, 256, 0, stream>>>(hidden, wfrag, fc_b, emws);
  crf_half_kernel<<<4 * BB, 64, 0, stream>>>(emws, amask, st, en, tr,
                                             amw, bmw, avw, bvw, bpws, fpws);
  finish_kernel<<<BB, 64, 0, stream>>>(emws, amask, labels, st, en, tr,
                                       amw, bmw, avw, bvw, bpws, fpws, out);
}